// Round 10
// baseline (135.125 us; speedup 1.0000x reference)
//
#include <hip/hip_runtime.h>
#include <hip/hip_bf16.h>

// u[b,o,y,x] = sum_d dist(p,d) * t[b,d,o],  t = v@W^T + bias
// GEMM: out[col*9216 + p] = sum_d D[p,d] * T2[col][d],  col = b*32+o
// All-f16 path: T2 f16; dist computed packed (v_pk_fma_f16 + v_sqrt_f16);
// mfma_f32_32x32x16_f16. NO LDS, NO barriers: B streamed global->reg
// per wave (L1/L2-resident, XCD-pinned k-chunks), depth-1 reg prefetch.
// Wave = 64r x 128c (acc 2x4); block = 4 waves stacked rows = 256r x 128c.
// Grid = 36 rowblk x 2 colblk x 8 ksplit = 576. f16 partials + reduce.

typedef float     f32x4  __attribute__((ext_vector_type(4)));
typedef float     f32x16 __attribute__((ext_vector_type(16)));
typedef _Float16  f16x2  __attribute__((ext_vector_type(2)));
typedef _Float16  f16x4  __attribute__((ext_vector_type(4)));
typedef _Float16  f16x8  __attribute__((ext_vector_type(8)));

#define NPTS   9216      // 96*96
#define CIN    32
#define COUT   32
#define NCOLS  256       // 8 batches * 32 cout
#define SCALEF (1.0f / 95.0f)
#define OUTN   (NCOLS * NPTS)
#define NSPLIT 8
#define KCHUNK 1152      // 12*96
#define NSTEPS 72        // KCHUNK/16

// ---------------- Kernel 1: projection  T2[col][d] = f16(v . W^T + b) -----
__global__ __launch_bounds__(256) void proj_kernel(
    const float* __restrict__ v, const float* __restrict__ W,
    const float* __restrict__ bias, _Float16* __restrict__ T2)
{
    __shared__ float Wl[COUT * CIN];
    __shared__ float bl[COUT];
    const int t = threadIdx.x;
    for (int i = t; i < COUT * CIN; i += 256) Wl[i] = W[i];
    if (t < COUT) bl[t] = bias[t];
    __syncthreads();

    const int b = blockIdx.y;
    const int d = blockIdx.x * 256 + t;
    const float* vb = v + (size_t)b * CIN * NPTS + d;

    float acc[COUT];
#pragma unroll
    for (int o = 0; o < COUT; ++o) acc[o] = bl[o];
#pragma unroll 4
    for (int c = 0; c < CIN; ++c) {
        const float vv = vb[(size_t)c * NPTS];
#pragma unroll
        for (int o = 0; o < COUT; ++o) acc[o] += vv * Wl[o * CIN + c];
    }
#pragma unroll
    for (int o = 0; o < COUT; ++o)
        T2[(size_t)(b * COUT + o) * NPTS + d] = (_Float16)acc[o];
}

// ---------------- A-fragment generator (all f16, packed) ------------------
// a[j] = sqrt(((xo-j)*S)^2 + (dyi*S)^2), j=0..7, as f16x8.
__device__ __forceinline__ f16x8 agen(int xo, int dyi) {
    const _Float16 hS = (_Float16)SCALEF;
    const _Float16 hxo = (_Float16)xo;      // exact, |xo| <= 103
    const _Float16 hdy = (_Float16)dyi * hS;
    const _Float16 dy2 = hdy * hdy;
    const f16x2 xov  = { hxo, hxo };
    const f16x2 sv   = { hS, hS };
    const f16x2 dy2v = { dy2, dy2 };
    union { unsigned int u[4]; f16x8 v; } pk;
#pragma unroll
    for (int q = 0; q < 4; ++q) {
        const f16x2 mj = { (_Float16)(-(float)(2*q) * SCALEF),
                           (_Float16)(-(float)(2*q+1) * SCALEF) };
        const f16x2 dx = xov * sv + mj;          // v_pk_fma_f16
        const f16x2 sq = dx * dx + dy2v;         // v_pk_fma_f16
        const unsigned int squ = __builtin_bit_cast(unsigned int, sq);
        unsigned int rlo, rhi;
        asm("v_sqrt_f16 %0, %1" : "=v"(rlo) : "v"(squ));         // low half
        asm("v_sqrt_f16 %0, %1" : "=v"(rhi) : "v"(squ >> 16));   // high half
        pk.u[q] = __builtin_amdgcn_perm(rhi, rlo, 0x05040100u);
    }
    return pk.v;
}

// ---------------- Kernel 2: implicit-D GEMM, no LDS, no barriers ----------
__global__ __launch_bounds__(256, 2) void gemm_kernel(
    const _Float16* __restrict__ T2, void* __restrict__ dst, int usePartial)
{
    const int tid  = threadIdx.x;
    const int wid  = tid >> 6;
    const int lane = tid & 63;
    const int l31  = lane & 31;
    const int hi   = lane >> 5;          // k-half within frag

    const int bid = blockIdx.x;
    const int z   = bid & 7;             // k-chunk id == XCD (round-robin)
    const int w   = bid >> 3;            // 0..71
    const int cb  = w & 1;               // col-block 0..1
    const int x   = w >> 1;              // row-block 0..35
    const int koff = z * KCHUNK;
    const int colBase = cb * 128;

    const int pbase = x * 256 + wid * 64;
    const int prow0 = pbase + l31;       // m=0 row
    const int prow1 = prow0 + 32;        // m=1 row
    const int yp0 = prow0 / 96, xp0 = prow0 - yp0 * 96;
    const int yp1 = prow1 / 96, xp1 = prow1 - yp1 * 96;
    const int xph0 = xp0 - hi * 8;       // hi fold pre-applied
    const int xph1 = xp1 - hi * 8;

    // per-lane B base pointers for the 4 col tiles (lane l31 = col)
    const _Float16* bb0 = T2 + (size_t)(colBase +      l31) * NPTS + koff + hi * 8;
    const _Float16* bb1 = T2 + (size_t)(colBase + 32 + l31) * NPTS + koff + hi * 8;
    const _Float16* bb2 = T2 + (size_t)(colBase + 64 + l31) * NPTS + koff + hi * 8;
    const _Float16* bb3 = T2 + (size_t)(colBase + 96 + l31) * NPTS + koff + hi * 8;

    f32x16 acc[2][4];
#pragma unroll
    for (int m = 0; m < 2; ++m)
#pragma unroll
        for (int n = 0; n < 4; ++n) acc[m][n] = (f32x16)(0.0f);

    // prologue: load step 0
    f16x8 bc0 = *(const f16x8*)(bb0);
    f16x8 bc1 = *(const f16x8*)(bb1);
    f16x8 bc2 = *(const f16x8*)(bb2);
    f16x8 bc3 = *(const f16x8*)(bb3);

    int xs = 0, ys = z * 12;             // k-step coords (koff%96==0)
    for (int t = 0; t < NSTEPS; ++t) {
        // depth-1 prefetch of next step (clamped on last iter)
        const size_t toff = (size_t)((t + 1 < NSTEPS) ? t + 1 : t) * 16;
        const f16x8 bn0 = *(const f16x8*)(bb0 + toff);
        const f16x8 bn1 = *(const f16x8*)(bb1 + toff);
        const f16x8 bn2 = *(const f16x8*)(bb2 + toff);
        const f16x8 bn3 = *(const f16x8*)(bb3 + toff);

        // A fragments (k never straddles x=96 within a 16-step: 96%16==0)
        const f16x8 a0 = agen(xph0 - xs, yp0 - ys);
        const f16x8 a1 = agen(xph1 - xs, yp1 - ys);

        acc[0][0] = __builtin_amdgcn_mfma_f32_32x32x16_f16(a0, bc0, acc[0][0], 0, 0, 0);
        acc[1][0] = __builtin_amdgcn_mfma_f32_32x32x16_f16(a1, bc0, acc[1][0], 0, 0, 0);
        acc[0][1] = __builtin_amdgcn_mfma_f32_32x32x16_f16(a0, bc1, acc[0][1], 0, 0, 0);
        acc[1][1] = __builtin_amdgcn_mfma_f32_32x32x16_f16(a1, bc1, acc[1][1], 0, 0, 0);
        acc[0][2] = __builtin_amdgcn_mfma_f32_32x32x16_f16(a0, bc2, acc[0][2], 0, 0, 0);
        acc[1][2] = __builtin_amdgcn_mfma_f32_32x32x16_f16(a1, bc2, acc[1][2], 0, 0, 0);
        acc[0][3] = __builtin_amdgcn_mfma_f32_32x32x16_f16(a0, bc3, acc[0][3], 0, 0, 0);
        acc[1][3] = __builtin_amdgcn_mfma_f32_32x32x16_f16(a1, bc3, acc[1][3], 0, 0, 0);

        bc0 = bn0; bc1 = bn1; bc2 = bn2; bc3 = bn3;
        xs += 16; if (xs == 96) { xs = 0; ++ys; }
    }

    // epilogue: 32x32 C/D: col=lane&31, row=(r&3)+8*(r>>2)+4*hi
    if (usePartial) {
        _Float16* pb = (_Float16*)dst + (size_t)z * OUTN;
#pragma unroll
        for (int m = 0; m < 2; ++m)
#pragma unroll
            for (int n = 0; n < 4; ++n) {
                const int col = colBase + n * 32 + l31;
                _Float16* ob = pb + (size_t)col * NPTS + pbase + m * 32 + 4 * hi;
#pragma unroll
                for (int q = 0; q < 4; ++q) {
                    f16x4 h = { (_Float16)acc[m][n][4*q],
                                (_Float16)acc[m][n][4*q+1],
                                (_Float16)acc[m][n][4*q+2],
                                (_Float16)acc[m][n][4*q+3] };
                    *(f16x4*)(ob + q * 8) = h;
                }
            }
    } else {
        float* ob0 = (float*)dst;
#pragma unroll
        for (int m = 0; m < 2; ++m)
#pragma unroll
            for (int n = 0; n < 4; ++n) {
                const int col = colBase + n * 32 + l31;
                float* ob = ob0 + (size_t)col * NPTS + pbase + m * 32 + 4 * hi;
#pragma unroll
                for (int q = 0; q < 4; ++q)
#pragma unroll
                    for (int r = 0; r < 4; ++r)
                        atomicAdd(ob + q * 8 + r, acc[m][n][4*q+r]);
            }
    }
}

// ---------------- Kernel 3: reduce NSPLIT f16 partials --------------------
__global__ __launch_bounds__(256) void reduce_kernel(
    const _Float16* __restrict__ part, float* __restrict__ out)
{
    const size_t i = ((size_t)blockIdx.x * 256 + threadIdx.x) * 8;
    float a[8] = {};
#pragma unroll
    for (int s = 0; s < NSPLIT; ++s) {
        f16x8 v = *(const f16x8*)(part + (size_t)s * OUTN + i);
#pragma unroll
        for (int r = 0; r < 8; ++r) a[r] += (float)v[r];
    }
    f32x4 o0 = { a[0], a[1], a[2], a[3] };
    f32x4 o1 = { a[4], a[5], a[6], a[7] };
    *(f32x4*)(out + i)     = o0;
    *(f32x4*)(out + i + 4) = o1;
}

extern "C" void kernel_launch(void* const* d_in, const int* in_sizes, int n_in,
                              void* d_out, int out_size, void* d_ws, size_t ws_size,
                              hipStream_t stream) {
    const float* v    = (const float*)d_in[0];  // (8,32,96,96)
    const float* W    = (const float*)d_in[1];  // (32,32)
    const float* bias = (const float*)d_in[2];  // (32,)
    float* out = (float*)d_out;                 // (8,32,96,96) f32

    _Float16* T2 = (_Float16*)d_ws;             // 256 x 9216 f16 = 4.72 MB
    const size_t t2b = (size_t)NCOLS * NPTS * 2;
    _Float16* partial = (_Float16*)((char*)d_ws + t2b);
    const size_t need = t2b + (size_t)NSPLIT * OUTN * 2;  // + 37.7 MB
    const int usePartial = (ws_size >= need) ? 1 : 0;

    proj_kernel<<<dim3(36, 8), 256, 0, stream>>>(v, W, bias, T2);
    if (usePartial) {
        gemm_kernel<<<72 * NSPLIT, 256, 0, stream>>>(T2, partial, 1);
        reduce_kernel<<<OUTN / 2048, 256, 0, stream>>>(partial, out);
    } else {
        hipMemsetAsync(d_out, 0, (size_t)out_size * sizeof(float), stream);
        gemm_kernel<<<72 * NSPLIT, 256, 0, stream>>>(T2, out, 0);
    }
}

// Round 14
// 81.389 us; speedup vs baseline: 1.6602x; 1.6602x over previous
//
#include <hip/hip_runtime.h>
#include <hip/hip_bf16.h>

// u[b,o,y,x] = sum_d dist(p,d) * t[b,d,o],  t = v@W^T + bias
// GEMM: out[col*9216 + p] = sum_d D[p,d] * T2[col][d],  col = b*32+o
// D generated in registers (sub+fma+sqrt+cvt_pk). 32x32x16 MFMA.
// Block = 256 thr = 4 waves (2 rg x 2 cg); wave = 64r x 128c (acc 2x4 =
// 128 AGPR; B-frag reused by 2 MFMAs; A-dup = 2 chip-wide).
// Block tile 128r x 256c, BK=64 dbuf (64KB LDS) -> 2 blocks/CU.
// K split 7 ways (6x1344 + 1152), grid = 504 = fully resident, no tail.
// EXACT resubmission of the round-9 passing kernel (determinism check).

typedef __bf16    bf16x8 __attribute__((ext_vector_type(8)));
typedef float     f32x4  __attribute__((ext_vector_type(4)));
typedef float     f32x16 __attribute__((ext_vector_type(16)));
typedef _Float16  f16x4  __attribute__((ext_vector_type(4)));
typedef _Float16  f16x8  __attribute__((ext_vector_type(8)));

#define NPTS   9216      // 96*96
#define CIN    32
#define COUT   32
#define NCOLS  256       // 8 batches * 32 cout
#define SCALE  (1.0f / 95.0f)
#define OUTN   (NCOLS * NPTS)
#define NSPLIT 7
#define KCHUNK 1344      // 14*96 (last chunk 1152 = 12*96)

// ---------------- Kernel 1: projection  T2[col][d] = bf16(v . W^T + b) ----
__global__ __launch_bounds__(256) void proj_kernel(
    const float* __restrict__ v, const float* __restrict__ W,
    const float* __restrict__ bias, __bf16* __restrict__ T2)
{
    __shared__ float Wl[COUT * CIN];
    __shared__ float bl[COUT];
    const int t = threadIdx.x;
    for (int i = t; i < COUT * CIN; i += 256) Wl[i] = W[i];
    if (t < COUT) bl[t] = bias[t];
    __syncthreads();

    const int b = blockIdx.y;
    const int d = blockIdx.x * 256 + t;
    const float* vb = v + (size_t)b * CIN * NPTS + d;

    float acc[COUT];
#pragma unroll
    for (int o = 0; o < COUT; ++o) acc[o] = bl[o];
#pragma unroll 4
    for (int c = 0; c < CIN; ++c) {
        const float vv = vb[(size_t)c * NPTS];
#pragma unroll
        for (int o = 0; o < COUT; ++o) acc[o] += vv * Wl[o * CIN + c];
    }
#pragma unroll
    for (int o = 0; o < COUT; ++o)
        T2[(size_t)(b * COUT + o) * NPTS + d] = (__bf16)acc[o];
}

// ---------------- A-fragment generator -----------------------------------
// 8 dist values -> bf16x8 via v_cvt_pk_bf16_f32 (1 instr per 2 elems).
__device__ __forceinline__ bf16x8 agen(float dx, float dy2) {
    float f[8];
#pragma unroll
    for (int j = 0; j < 8; ++j) {
        f[j] = __builtin_amdgcn_sqrtf(__builtin_fmaf(dx, dx, dy2));
        dx -= SCALE;
    }
    union { unsigned int u[4]; bf16x8 v; } pk;
#pragma unroll
    for (int q = 0; q < 4; ++q)
        asm("v_cvt_pk_bf16_f32 %0, %1, %2"
            : "=v"(pk.u[q]) : "v"(f[2*q]), "v"(f[2*q+1]));
    return pk.v;
}

// ---------------- Kernel 2: implicit-D GEMM ------------------------------
__global__ __launch_bounds__(256, 2) void gemm_kernel(
    const __bf16* __restrict__ T2, void* __restrict__ dst, int usePartial)
{
    __shared__ __align__(1024) unsigned char lds[2][32768];

    const int tid  = threadIdx.x;
    const int wid  = tid >> 6;
    const int lane = tid & 63;
    const int l31  = lane & 31;
    const int hi   = lane >> 5;      // k-half within frag
    const int rg   = wid >> 1;       // row group 0..1 (64 rows)
    const int cg   = wid & 1;        // col group 0..1 (128 cols)

    const int bid = blockIdx.x;
    const int z   = bid / 72;        // k-chunk id 0..6
    const int x   = bid - z * 72;    // row-block id 0..71
    const int koff = z * KCHUNK;
    const int nt   = (z == NSPLIT - 1) ? 18 : 21;   // BK=64 tiles

    const int pbase = x * 128 + rg * 64;
    const int prow0 = pbase + l31;                  // m=0 row
    const int prow1 = prow0 + 32;                   // m=1 row
    const int yp0 = prow0 / 96, xp0 = prow0 - yp0 * 96;
    const int yp1 = prow1 / 96, xp1 = prow1 - yp1 * 96;
    const int xph0 = xp0 - hi * 8;   // hi fold pre-applied
    const int xph1 = xp1 - hi * 8;

    // hoisted LDS B-read byte offsets boff[s][n] (lane-constant)
    int boff[4][4];
#pragma unroll
    for (int s = 0; s < 4; ++s)
#pragma unroll
        for (int n = 0; n < 4; ++n) {
            const int col  = cg * 128 + n * 32 + l31;
            const int slot = (s * 2 + hi) ^ (col & 7);
            boff[s][n] = col * 128 + slot * 16;
        }

    // staging: 8 x gload16 per buffer; dest linear tid*16 within 4KB rows;
    // source chunk pre-swizzled so LDS slot = logical ^ (col&7).
    const int scol = tid >> 3;               // col 0..31 (+32*i)
    const int sch  = (tid & 7) ^ (scol & 7);
    const __bf16* gsrc = T2 + (size_t)scol * NPTS + koff + sch * 8;
    const int ldst = tid * 16;

    auto stage = [&](int buf, int kt) {
#pragma unroll
        for (int i = 0; i < 8; ++i)
            __builtin_amdgcn_global_load_lds(
                (const __attribute__((address_space(1))) void*)
                    (gsrc + (size_t)kt * 64 + (size_t)i * 32 * NPTS),
                (__attribute__((address_space(3))) void*)
                    (&lds[buf][i * 4096 + ldst]),
                16, 0, 0);
    };

    f32x16 acc[2][4];
#pragma unroll
    for (int m = 0; m < 2; ++m)
#pragma unroll
        for (int n = 0; n < 4; ++n) acc[m][n] = (f32x16)(0.0f);

    stage(0, 0);
    __syncthreads();

    int xt = 0, yt = z * 14;         // k-tile base coords (koff%96==0)
    int cur = 0;
    for (int kt = 0; kt < nt; ++kt) {
        if (kt + 1 < nt) stage(cur ^ 1, kt + 1);
        const unsigned char* Lb = lds[cur];

#pragma unroll
        for (int s = 0; s < 4; ++s) {        // 4 k-steps of 16
            const int xr = xt + s * 16;
            const int xk = (xr >= 96) ? xr - 96 : xr;
            const int yk = (xr >= 96) ? yt + 1  : yt;
            const float dy0 = (float)(yp0 - yk) * SCALE;
            const float dy1 = (float)(yp1 - yk) * SCALE;
            const bf16x8 a0 = agen((float)(xph0 - xk) * SCALE, dy0 * dy0);
            const bf16x8 a1 = agen((float)(xph1 - xk) * SCALE, dy1 * dy1);
#pragma unroll
            for (int n = 0; n < 4; ++n) {
                const bf16x8 b = *(const bf16x8*)(Lb + boff[s][n]);
                acc[0][n] = __builtin_amdgcn_mfma_f32_32x32x16_bf16(
                    a0, b, acc[0][n], 0, 0, 0);
                acc[1][n] = __builtin_amdgcn_mfma_f32_32x32x16_bf16(
                    a1, b, acc[1][n], 0, 0, 0);
            }
        }
        xt += 64; if (xt >= 96) { xt -= 96; ++yt; }
        __syncthreads();
        cur ^= 1;
    }

    // epilogue: 32x32 C/D: col=lane&31, row=(r&3)+8*(r>>2)+4*hi
    if (usePartial) {
        _Float16* pb = (_Float16*)dst + (size_t)z * OUTN;
#pragma unroll
        for (int m = 0; m < 2; ++m)
#pragma unroll
            for (int n = 0; n < 4; ++n) {
                const int col = cg * 128 + n * 32 + l31;
                _Float16* ob = pb + (size_t)col * NPTS + pbase + m * 32 + 4 * hi;
#pragma unroll
                for (int q = 0; q < 4; ++q) {
                    f16x4 h = { (_Float16)acc[m][n][4*q],
                                (_Float16)acc[m][n][4*q+1],
                                (_Float16)acc[m][n][4*q+2],
                                (_Float16)acc[m][n][4*q+3] };
                    *(f16x4*)(ob + q * 8) = h;
                }
            }
    } else {
        float* ob0 = (float*)dst;
#pragma unroll
        for (int m = 0; m < 2; ++m)
#pragma unroll
            for (int n = 0; n < 4; ++n) {
                const int col = cg * 128 + n * 32 + l31;
                float* ob = ob0 + (size_t)col * NPTS + pbase + m * 32 + 4 * hi;
#pragma unroll
                for (int q = 0; q < 4; ++q)
#pragma unroll
                    for (int r = 0; r < 4; ++r)
                        atomicAdd(ob + q * 8 + r, acc[m][n][4*q+r]);
            }
    }
}

// ---------------- Kernel 3: reduce NSPLIT f16 partials --------------------
__global__ __launch_bounds__(256) void reduce_kernel(
    const _Float16* __restrict__ part, float* __restrict__ out)
{
    const size_t i = ((size_t)blockIdx.x * 256 + threadIdx.x) * 8;
    float a[8] = {};
#pragma unroll
    for (int s = 0; s < NSPLIT; ++s) {
        f16x8 v = *(const f16x8*)(part + (size_t)s * OUTN + i);
#pragma unroll
        for (int r = 0; r < 8; ++r) a[r] += (float)v[r];
    }
    f32x4 o0 = { a[0], a[1], a[2], a[3] };
    f32x4 o1 = { a[4], a[5], a[6], a[7] };
    *(f32x4*)(out + i)     = o0;
    *(f32x4*)(out + i + 4) = o1;
}

extern "C" void kernel_launch(void* const* d_in, const int* in_sizes, int n_in,
                              void* d_out, int out_size, void* d_ws, size_t ws_size,
                              hipStream_t stream) {
    const float* v    = (const float*)d_in[0];  // (8,32,96,96)
    const float* W    = (const float*)d_in[1];  // (32,32)
    const float* bias = (const float*)d_in[2];  // (32,)
    float* out = (float*)d_out;                 // (8,32,96,96) f32

    __bf16* T2 = (__bf16*)d_ws;                 // 256 x 9216 bf16 = 4.72 MB
    const size_t t2b = (size_t)NCOLS * NPTS * 2;
    _Float16* partial = (_Float16*)((char*)d_ws + t2b);
    const size_t need = t2b + (size_t)NSPLIT * OUTN * 2;  // + 33 MB
    const int usePartial = (ws_size >= need) ? 1 : 0;

    proj_kernel<<<dim3(36, 8), 256, 0, stream>>>(v, W, bias, T2);
    if (usePartial) {
        gemm_kernel<<<72 * NSPLIT, 256, 0, stream>>>(T2, partial, 1);
        reduce_kernel<<<OUTN / 2048, 256, 0, stream>>>(partial, out);
    } else {
        hipMemsetAsync(d_out, 0, (size_t)out_size * sizeof(float), stream);
        gemm_kernel<<<72 * NSPLIT, 256, 0, stream>>>(T2, out, 0);
    }
}